// Round 3
// baseline (926.987 us; speedup 1.0000x reference)
//
#include <hip/hip_runtime.h>
#include <stdint.h>

#define N_CLUSTERS 100
#define M 10
#define HS 5
#define HM 50
#define GROUP 64           // batch rows per block
#define NWAVE 16           // 1024 threads
#define XPITCH_B 2012      // bytes per staged bf16 row (503 words, odd -> 2-way free)
#define EPITCH 101         // fp32 per err row
#define HPITCH 52          // u16 per hm row

// LDS layout (bytes):
//   xg   : 64*2012 = 128768 @ 0   (aliased by part[16*64] f32 at the end)
//   err  : 64*101*4 = 25856 @ 128768
//   hm   : 64*52*2  =  6656 @ 154624
#define LDS_ERR   128768
#define LDS_HM    154624
#define LDS_TOTAL 161280

__device__ __forceinline__ uint32_t f2bf(float f) {
    uint32_t u = __float_as_uint(f);
    return (u + 0x7fffu + ((u >> 16) & 1u)) >> 16;   // RNE
}
__device__ __forceinline__ float bf2f(uint32_t h) {
    return __uint_as_float(h << 16);
}
// VGPR-resident zero the compiler cannot fold -> forces VECTOR loads (vmcnt)
// for wave-uniform weight reads, keeping them OFF the lgkmcnt path that
// ds_read shares with s_load (mixing forces lgkmcnt(0) full serialization).
__device__ __forceinline__ int opaque_zero() {
    int z;
    asm("v_mov_b32 %0, 0" : "=v"(z));
    return z;
}

__global__ void __launch_bounds__(1024, 4) kitnet_kernel(
    const float* __restrict__ x,
    const int*   __restrict__ fi,
    const float* __restrict__ W_enc, const float* __restrict__ b_enc,
    const float* __restrict__ W_dec, const float* __restrict__ b_dec,
    const float* __restrict__ We1,   const float* __restrict__ be1,
    const float* __restrict__ Wd1,   const float* __restrict__ bd1,
    float* __restrict__ out)
{
    extern __shared__ char smem[];
    float*  errs = (float*) (smem + LDS_ERR);
    ushort* hmb  = (ushort*)(smem + LDS_HM);

    const int tid  = threadIdx.x;
    const int lane = tid & 63;
    const int w    = __builtin_amdgcn_readfirstlane(tid >> 6);
    const int b0   = blockIdx.x * GROUP;

    const int vz = opaque_zero();
    const int2*   fiv = (const int2*)  fi    + vz;   // idx c*5+p
    const float2* wev = (const float2*)W_enc + vz;   // idx c*25+p (flat c*50+m*5+k)
    const float*  bev = b_enc + vz;                  // idx c*5+k
    const float2* wdv = (const float2*)W_dec + vz;   // idx c*25+p (flat c*50+k*10+m)
    const float2* bdv = (const float2*)b_dec + vz;   // idx c*5+p
    const float*  we1v = We1 + vz;
    const float*  wd1v = Wd1 + vz;

    // ---- stage: 64 rows x 1000 fp32 (256 KB contiguous, coalesced) -> bf16 LDS ----
    const float4* xr = (const float4*)(x + (size_t)b0 * 1000);
    for (int i = tid; i < 16000; i += 1024) {
        float4 v = xr[i];
        int row = i / 250;
        int c4  = i - row * 250;
        char* p = smem + row * XPITCH_B + c4 * 8;
        *(uint32_t*)(p)     = f2bf(v.x) | (f2bf(v.y) << 16);
        *(uint32_t*)(p + 4) = f2bf(v.z) | (f2bf(v.w) << 16);
    }
    __syncthreads();

    // ---- cluster AEs: wave w -> clusters {w, w+16, ...}; lane = batch row ----
    const ushort* myrow = (const ushort*)(smem + lane * XPITCH_B);

    auto do_cluster = [&](int c) {
        int cols[M];
        #pragma unroll
        for (int p = 0; p < 5; ++p) {
            int2 t = fiv[c * 5 + p];
            cols[2 * p] = t.x; cols[2 * p + 1] = t.y;
        }
        float xv[M];
        #pragma unroll
        for (int m = 0; m < M; ++m) xv[m] = bf2f(myrow[cols[m]]);
        float h[HS];
        #pragma unroll
        for (int k = 0; k < HS; ++k) h[k] = bev[c * 5 + k];
        #pragma unroll
        for (int p = 0; p < 25; ++p) {
            float2 t = wev[c * 25 + p];
            h[(2 * p) % 5]     = __builtin_fmaf(xv[(2 * p) / 5],     t.x, h[(2 * p) % 5]);
            h[(2 * p + 1) % 5] = __builtin_fmaf(xv[(2 * p + 1) / 5], t.y, h[(2 * p + 1) % 5]);
        }
        #pragma unroll
        for (int k = 0; k < HS; ++k) h[k] = fmaxf(h[k], 0.f);
        float rec[M];
        #pragma unroll
        for (int p = 0; p < 5; ++p) {
            float2 t = bdv[c * 5 + p];
            rec[2 * p] = t.x; rec[2 * p + 1] = t.y;
        }
        #pragma unroll
        for (int p = 0; p < 25; ++p) {
            float2 t = wdv[c * 25 + p];
            int k = (2 * p) / 10, m = (2 * p) % 10;
            rec[m]     = __builtin_fmaf(h[k], t.x, rec[m]);
            rec[m + 1] = __builtin_fmaf(h[k], t.y, rec[m + 1]);
        }
        float acc = 0.f;
        #pragma unroll
        for (int m = 0; m < M; ++m) {
            float d = xv[m] - rec[m];
            acc = __builtin_fmaf(d, d, acc);
        }
        errs[lane * EPITCH + c] = __builtin_sqrtf(acc * 0.1f);
    };

    #pragma unroll 2
    for (int t = 0; t < 6; ++t) do_cluster(w + 16 * t);
    if (w < 4) do_cluster(w + 96);
    __syncthreads();

    // ---- meta encoder: wave w -> hidden units j = w + 16*i ----
    const float* erow = errs + lane * EPITCH;
    {
        float hacc[4];
        #pragma unroll
        for (int i = 0; i < 4; ++i) {
            int j = w + NWAVE * i;
            hacc[i] = (j < HM) ? be1[j] : 0.f;
        }
        #pragma unroll 4
        for (int c = 0; c < N_CLUSTERS; ++c) {
            float e = erow[c];
            #pragma unroll
            for (int i = 0; i < 4; ++i) {
                int j = w + NWAVE * i;
                if (j < HM)
                    hacc[i] = __builtin_fmaf(e, we1v[c * HM + j], hacc[i]);
            }
        }
        #pragma unroll
        for (int i = 0; i < 4; ++i) {
            int j = w + NWAVE * i;
            if (j < HM)
                hmb[lane * HPITCH + j] = (ushort)f2bf(fmaxf(hacc[i], 0.f));
        }
    }
    __syncthreads();

    // ---- meta decoder + final RMS: wave w -> clusters {w, w+16, ...} ----
    float acc7[7];
    #pragma unroll
    for (int i = 0; i < 7; ++i) acc7[i] = 0.f;
    const uint32_t* hrow32 = (const uint32_t*)(hmb + lane * HPITCH);
    #pragma unroll
    for (int jc = 0; jc < 5; ++jc) {
        float hv[10];
        #pragma unroll
        for (int p = 0; p < 5; ++p) {
            uint32_t u = hrow32[jc * 5 + p];
            hv[2 * p]     = bf2f(u & 0xffffu);
            hv[2 * p + 1] = bf2f(u >> 16);
        }
        #pragma unroll
        for (int j2 = 0; j2 < 10; ++j2) {
            int j = jc * 10 + j2;
            #pragma unroll
            for (int i = 0; i < 7; ++i) {
                int c = w + NWAVE * i;
                if (c < N_CLUSTERS)
                    acc7[i] = __builtin_fmaf(hv[j2], wd1v[j * N_CLUSTERS + c], acc7[i]);
            }
        }
    }
    float facc = 0.f;
    #pragma unroll
    for (int i = 0; i < 7; ++i) {
        int c = w + NWAVE * i;
        if (c < N_CLUSTERS) {
            float e = erow[c];
            float d = e - (acc7[i] + bd1[c]);
            facc = __builtin_fmaf(d, d, facc);
        }
    }

    // ---- reduce 16 wave-partials per row (aliases dead xg region) ----
    float* part = (float*)smem;
    part[w * 64 + lane] = facc;
    __syncthreads();
    if (tid < 64) {
        float s = 0.f;
        #pragma unroll
        for (int i = 0; i < NWAVE; ++i) s += part[i * 64 + tid];
        float fe = __builtin_sqrtf(s * 0.01f);
        out[b0 + tid] = 1.f / (1.f + __expf(-fe));
    }
}

extern "C" void kernel_launch(void* const* d_in, const int* in_sizes, int n_in,
                              void* d_out, int out_size, void* d_ws, size_t ws_size,
                              hipStream_t stream) {
    const float* x     = (const float*)d_in[0];
    const int*   fi    = (const int*)  d_in[1];
    const float* W_enc = (const float*)d_in[2];
    const float* b_enc = (const float*)d_in[3];
    const float* W_dec = (const float*)d_in[4];
    const float* b_dec = (const float*)d_in[5];
    const float* We1   = (const float*)d_in[6];
    const float* be1   = (const float*)d_in[7];
    const float* Wd1   = (const float*)d_in[8];
    const float* bd1   = (const float*)d_in[9];
    float* out = (float*)d_out;

    (void)hipFuncSetAttribute((const void*)kitnet_kernel,
                              hipFuncAttributeMaxDynamicSharedMemorySize, LDS_TOTAL);
    kitnet_kernel<<<65536 / GROUP, 1024, LDS_TOTAL, stream>>>(
        x, fi, W_enc, b_enc, W_dec, b_dec, We1, be1, Wd1, bd1, out);
}

// Round 4
// 473.741 us; speedup vs baseline: 1.9567x; 1.9567x over previous
//
#include <hip/hip_runtime.h>
#include <stdint.h>

#define N_CLUSTERS 100
#define M 10
#define HS 5
#define HM 50
#define GROUP 64
#define NWAVE 16
#define XPITCH_B 2004      // bf16 row pitch: 501 words, odd -> 2-way bank = free

// LDS layout (bytes):
//  phase 0/1 resident:
//   xg    @ 0      : 64*2004 = 128256
//   lwe   @ 128256 : W_enc bf16, pitch 52 u16/cluster = 10400
//   lwd   @ 138656 : W_dec bf16, pitch 52 u16/cluster = 10400
//   errL  @ 149056 : err bf16 [row][c], pitch 102 u16 = 13056   -> total 162112
//  phase 2+ overlay on dead xg region:
//   we1t  @ 0      : We1^T bf16 [j][c], pitch 104 u16 = 10400
//   wd1t  @ 10400  : Wd1^T bf16 [c][j], pitch 56 u16  = 11200
//   hmT   @ 21600  : hm f32 [j][row], pitch 64        = 12800
//   part  @ 34400  : f32 [16][64]                     = 4096
#define O_WE1T 0
#define O_WD1T 10400
#define O_HMT  21600
#define O_PART 34400
#define O_LWE  128256
#define O_LWD  138656
#define O_ERR  149056
#define LDS_TOTAL 162112

__device__ __forceinline__ uint32_t f2bf(float f) {
    uint32_t u = __float_as_uint(f);
    return (u + 0x7fffu + ((u >> 16) & 1u)) >> 16;   // RNE
}
__device__ __forceinline__ float bf2f(uint32_t h) {
    return __uint_as_float(h << 16);
}
__device__ __forceinline__ void unpack2(uint32_t u, float& a, float& b) {
    a = __uint_as_float(u << 16);
    b = __uint_as_float(u & 0xffff0000u);
}

__global__ void __launch_bounds__(1024, 4) kitnet_kernel(
    const float* __restrict__ x,
    const int*   __restrict__ fi,
    const float* __restrict__ W_enc, const float* __restrict__ b_enc,
    const float* __restrict__ W_dec, const float* __restrict__ b_dec,
    const float* __restrict__ We1,   const float* __restrict__ be1,
    const float* __restrict__ Wd1,   const float* __restrict__ bd1,
    float* __restrict__ out)
{
    extern __shared__ char smem[];
    const int tid  = threadIdx.x;
    const int lane = tid & 63;
    const int w    = __builtin_amdgcn_readfirstlane(tid >> 6);
    const int b0   = blockIdx.x * GROUP;

    ushort* lwe  = (ushort*)(smem + O_LWE);
    ushort* lwd  = (ushort*)(smem + O_LWD);
    ushort* errL = (ushort*)(smem + O_ERR);

    // ---- phase 0: stage x rows (coalesced f4) + cluster weights (bf16) ----
    const float4* xr = (const float4*)(x + (size_t)b0 * 1000);
    for (int i = tid; i < 16000; i += 1024) {
        float4 v = xr[i];
        int row = i / 250;
        int c4  = i - row * 250;
        char* p = smem + row * XPITCH_B + c4 * 8;
        ((uint32_t*)p)[0] = f2bf(v.x) | (f2bf(v.y) << 16);
        ((uint32_t*)p)[1] = f2bf(v.z) | (f2bf(v.w) << 16);
    }
    for (int i = tid; i < 5000; i += 1024) {
        int c = i / 50, r = i - c * 50;
        lwe[c * 52 + r] = (ushort)f2bf(W_enc[i]);
        lwd[c * 52 + r] = (ushort)f2bf(W_dec[i]);
    }
    __syncthreads();

    // ---- phase 1: cluster AEs. wave w -> clusters {w, w+16, ...}; lane=row ----
    const ushort* myrow = (const ushort*)(smem + lane * XPITCH_B);
    {
        const int nc = (w < 4) ? 7 : 6;
        for (int t = 0; t < nc; ++t) {
            const int c = w + 16 * t;
            float xv[M];
            #pragma unroll
            for (int m = 0; m < M; ++m) {
                int col = fi[c * 10 + m];          // wave-uniform -> s_load (fi K$-resident)
                xv[m] = bf2f(myrow[col]);
            }
            // encoder: W_enc flat (c,m,k) pairs from LDS broadcast
            const uint32_t* wE = (const uint32_t*)(lwe + c * 52);
            float h[HS];
            #pragma unroll
            for (int k = 0; k < HS; ++k) h[k] = b_enc[c * 5 + k];   // s_load, K$
            #pragma unroll
            for (int p = 0; p < 25; ++p) {
                float a, b; unpack2(wE[p], a, b);
                const int i0 = 2 * p, i1 = 2 * p + 1;
                h[i0 % 5] = __builtin_fmaf(xv[i0 / 5], a, h[i0 % 5]);
                h[i1 % 5] = __builtin_fmaf(xv[i1 / 5], b, h[i1 % 5]);
            }
            #pragma unroll
            for (int k = 0; k < HS; ++k) h[k] = fmaxf(h[k], 0.f);
            // decoder: W_dec flat (c,k,m)
            const uint32_t* wD = (const uint32_t*)(lwd + c * 52);
            float rec[M];
            #pragma unroll
            for (int m = 0; m < M; ++m) rec[m] = b_dec[c * 10 + m]; // s_load, K$
            #pragma unroll
            for (int p = 0; p < 25; ++p) {
                float a, b; unpack2(wD[p], a, b);
                const int k = (2 * p) / 10, m = (2 * p) % 10;
                rec[m]     = __builtin_fmaf(h[k], a, rec[m]);
                rec[m + 1] = __builtin_fmaf(h[k], b, rec[m + 1]);
            }
            float acc = 0.f;
            #pragma unroll
            for (int m = 0; m < M; ++m) {
                float d = xv[m] - rec[m];
                acc = __builtin_fmaf(d, d, acc);
            }
            errL[lane * 102 + c] = (ushort)f2bf(__builtin_sqrtf(acc * 0.1f));
        }
    }
    __syncthreads();

    // ---- phase 2: stage meta weights transposed (bf16) into dead xg region ----
    ushort* we1t = (ushort*)(smem + O_WE1T);
    ushort* wd1t = (ushort*)(smem + O_WD1T);
    for (int i = tid; i < 5000; i += 1024) {
        int c = i / 50, j = i - c * 50;        // We1 flat (c,j)
        we1t[j * 104 + c] = (ushort)f2bf(We1[i]);
    }
    for (int i = tid; i < 5000; i += 1024) {
        int j = i / 100, c = i - j * 100;      // Wd1 flat (j,c)
        wd1t[c * 56 + j] = (ushort)f2bf(Wd1[i]);
    }
    __syncthreads();

    // ---- phase 3: meta encoder. waves 0..7; wave w -> j in {w, w+8, ...} ----
    float* hmT = (float*)(smem + O_HMT);
    if (w < 8) {
        const int nj = (w < 2) ? 7 : 6;
        float hacc[7];
        #pragma unroll
        for (int jj = 0; jj < 7; ++jj)
            hacc[jj] = (jj < nj) ? be1[w + 8 * jj] : 0.f;   // s_load, K$
        const uint32_t* eL32 = (const uint32_t*)(errL + lane * 102);
        #pragma unroll 1
        for (int ch = 0; ch < 13; ++ch) {       // c chunks of 8 (last = 4)
            const int ncp = (ch == 12) ? 2 : 4; // c-pairs in chunk
            float e[8];
            #pragma unroll
            for (int p = 0; p < 4; ++p) {
                if (p < ncp) unpack2(eL32[ch * 4 + p], e[2 * p], e[2 * p + 1]);
            }
            #pragma unroll
            for (int jj = 0; jj < 7; ++jj) {
                if (jj < nj) {
                    const int j = w + 8 * jj;
                    uint4 wv = *(const uint4*)(we1t + j * 104 + ch * 8);  // 8 bf16, uniform
                    float wf[8];
                    unpack2(wv.x, wf[0], wf[1]); unpack2(wv.y, wf[2], wf[3]);
                    unpack2(wv.z, wf[4], wf[5]); unpack2(wv.w, wf[6], wf[7]);
                    #pragma unroll
                    for (int q = 0; q < 8; ++q)
                        if (q < 2 * ncp)
                            hacc[jj] = __builtin_fmaf(e[q], wf[q], hacc[jj]);
                }
            }
        }
        #pragma unroll
        for (int jj = 0; jj < 7; ++jj)
            if (jj < nj)
                hmT[(w + 8 * jj) * 64 + lane] = fmaxf(hacc[jj], 0.f);
    }
    __syncthreads();

    // ---- phase 4: meta decoder + final RMS. wave w -> clusters {w, w+16, ...} ----
    float hm[HM];
    #pragma unroll
    for (int j = 0; j < HM; ++j) hm[j] = hmT[j * 64 + lane];   // lane-consecutive b32
    float facc = 0.f;
    {
        const int nc = (w < 4) ? 7 : 6;
        for (int t = 0; t < nc; ++t) {
            const int c = w + 16 * t;
            float er = bf2f(errL[lane * 102 + c]);
            float r0 = bd1[c], r1 = 0.f;                        // s_load, K$
            #pragma unroll
            for (int jc = 0; jc < 7; ++jc) {    // j chunks of 8 (48..55 tail masked)
                uint4 wv = *(const uint4*)(wd1t + c * 56 + jc * 8);  // uniform b128
                float wf[8];
                unpack2(wv.x, wf[0], wf[1]); unpack2(wv.y, wf[2], wf[3]);
                unpack2(wv.z, wf[4], wf[5]); unpack2(wv.w, wf[6], wf[7]);
                #pragma unroll
                for (int q = 0; q < 8; q += 2) {
                    const int j = jc * 8 + q;
                    if (j < HM)     r0 = __builtin_fmaf(hm[j],     wf[q],     r0);
                    if (j + 1 < HM) r1 = __builtin_fmaf(hm[j + 1], wf[q + 1], r1);
                }
            }
            float d = er - (r0 + r1);
            facc = __builtin_fmaf(d, d, facc);
        }
    }
    float* part = (float*)(smem + O_PART);
    part[w * 64 + lane] = facc;
    __syncthreads();
    if (tid < 64) {
        float s = 0.f;
        #pragma unroll
        for (int i = 0; i < NWAVE; ++i) s += part[i * 64 + tid];
        float fe = __builtin_sqrtf(s * 0.01f);
        out[b0 + tid] = 1.f / (1.f + __expf(-fe));
    }
}

extern "C" void kernel_launch(void* const* d_in, const int* in_sizes, int n_in,
                              void* d_out, int out_size, void* d_ws, size_t ws_size,
                              hipStream_t stream) {
    const float* x     = (const float*)d_in[0];
    const int*   fi    = (const int*)  d_in[1];
    const float* W_enc = (const float*)d_in[2];
    const float* b_enc = (const float*)d_in[3];
    const float* W_dec = (const float*)d_in[4];
    const float* b_dec = (const float*)d_in[5];
    const float* We1   = (const float*)d_in[6];
    const float* be1   = (const float*)d_in[7];
    const float* Wd1   = (const float*)d_in[8];
    const float* bd1   = (const float*)d_in[9];
    float* out = (float*)d_out;

    (void)hipFuncSetAttribute((const void*)kitnet_kernel,
                              hipFuncAttributeMaxDynamicSharedMemorySize, LDS_TOTAL);
    kitnet_kernel<<<65536 / GROUP, 1024, LDS_TOTAL, stream>>>(
        x, fi, W_enc, b_enc, W_dec, b_dec, We1, be1, Wd1, bd1, out);
}

// Round 5
// 434.158 us; speedup vs baseline: 2.1351x; 1.0912x over previous
//
#include <hip/hip_runtime.h>
#include <stdint.h>

typedef _Float16 h2 __attribute__((ext_vector_type(2)));

#define N_CLUSTERS 100
#define M 10
#define HS 5
#define HM 50
#define GROUP 64
#define NWAVE 16
#define XPITCH_B 2004      // f16 row pitch: 501 words, odd -> 2-way bank = free

// LDS layout (bytes):
//  resident:
//   xg   @ 0      : 64*2004 = 128256   (overlaid after phase 1)
//   lwe  @ 128256 : W_enc f16x2 [c][k*5+p], pitch 104 B  = 10400
//   lwd  @ 138656 : W_dec f16x2 [c][m*3+q], pitch 120 B  = 12000
//   errL @ 150656 : err f16 [row][c], pitch 200 B        = 12800  -> 163456
//  overlay on dead xg:
//   we1p @ 0      : We1^T f16x2 [j][cp], pitch 104 B     = 5200
//   wd1p @ 5200   : Wd1^T f16x2 [c][jp], pitch 104 B     = 10400
//   hmp  @ 15600  : hm f16x2 [jp][row] u32               = 6400
//   part @ 22000  : f32 [16][64]                         = 4096
#define O_WE1T 0
#define O_WD1T 5200
#define O_HMT  15600
#define O_PART 22000
#define O_LWE  128256
#define O_LWD  138656
#define O_ERR  150656
#define LDS_TOTAL 163456

__device__ __forceinline__ float fdot2(uint32_t a, uint32_t b, float c) {
    return __builtin_amdgcn_fdot2(__builtin_bit_cast(h2, a),
                                  __builtin_bit_cast(h2, b), c, false);
}
__device__ __forceinline__ uint32_t pk2(float a, float b) {
    return __builtin_bit_cast(uint32_t, __builtin_amdgcn_cvt_pkrtz(a, b));
}
__device__ __forceinline__ float h2f(unsigned short u) {
    return (float)__builtin_bit_cast(_Float16, u);
}

__global__ void __launch_bounds__(1024) kitnet_kernel(
    const float* __restrict__ x,
    const int*   __restrict__ fi,
    const float* __restrict__ W_enc, const float* __restrict__ b_enc,
    const float* __restrict__ W_dec, const float* __restrict__ b_dec,
    const float* __restrict__ We1,   const float* __restrict__ be1,
    const float* __restrict__ Wd1,   const float* __restrict__ bd1,
    float* __restrict__ out)
{
    extern __shared__ char smem[];
    const int tid  = threadIdx.x;
    const int lane = tid & 63;
    const int w    = __builtin_amdgcn_readfirstlane(tid >> 6);
    const int b0   = blockIdx.x * GROUP;

    uint32_t* lweU = (uint32_t*)(smem + O_LWE);   // pitch 26 u32
    uint32_t* lwdU = (uint32_t*)(smem + O_LWD);   // pitch 30 u32
    unsigned short* errL = (unsigned short*)(smem + O_ERR); // pitch 100 u16

    // ---- phase 0: stage x (coalesced f4 -> pkrtz f16x2) + cluster weights ----
    const float4* xr = (const float4*)(x + (size_t)b0 * 1000);
    for (int i = tid; i < 16000; i += 1024) {
        float4 v = xr[i];
        int row = i / 250;
        int c4  = i - row * 250;
        uint32_t* p = (uint32_t*)(smem + row * XPITCH_B + c4 * 8);
        p[0] = pk2(v.x, v.y);
        p[1] = pk2(v.z, v.w);
    }
    for (int i = tid; i < 2500; i += 1024) {       // W_enc -> [c][k*5+p] m-pairs
        int c = i / 25, r = i - c * 25;
        int k = r / 5, pp = r - k * 5;
        lweU[c * 26 + r] = pk2(W_enc[c * 50 + (2 * pp) * 5 + k],
                               W_enc[c * 50 + (2 * pp + 1) * 5 + k]);
    }
    for (int i = tid; i < 3000; i += 1024) {       // W_dec -> [c][m*3+q] k-pairs
        int c = i / 30, r = i - c * 30;
        int m = r / 3, q = r - m * 3;
        float lo = W_dec[c * 50 + (2 * q) * 10 + m];
        float hi = (q == 2) ? 0.f : W_dec[c * 50 + (2 * q + 1) * 10 + m];
        lwdU[c * 30 + r] = pk2(lo, hi);
    }
    __syncthreads();

    // ---- phase 1: cluster AEs. wave w -> clusters {w, w+16,...}; lane = row ----
    const unsigned short* myrow = (const unsigned short*)(smem + lane * XPITCH_B);
    auto do_cluster = [&](int c) {
        int cols[M];
        #pragma unroll
        for (int m = 0; m < M; ++m) cols[m] = fi[c * 10 + m];   // uniform s_load
        uint32_t xpk[5];
        #pragma unroll
        for (int p = 0; p < 5; ++p)
            xpk[p] = (uint32_t)myrow[cols[2 * p]] |
                     ((uint32_t)myrow[cols[2 * p + 1]] << 16);
        // encoder: 25 dot2
        const uint2* eW = (const uint2*)(lweU + c * 26);
        uint32_t wreg[25];
        #pragma unroll
        for (int q = 0; q < 12; ++q) { uint2 t = eW[q]; wreg[2*q] = t.x; wreg[2*q+1] = t.y; }
        wreg[24] = (lweU + c * 26)[24];
        float h[HS];
        #pragma unroll
        for (int k = 0; k < HS; ++k) h[k] = b_enc[c * 5 + k];
        #pragma unroll
        for (int k = 0; k < HS; ++k) {
            #pragma unroll
            for (int p = 0; p < 5; ++p)
                h[k] = fdot2(xpk[p], wreg[k * 5 + p], h[k]);
        }
        uint32_t hp[3];
        hp[0] = pk2(fmaxf(h[0], 0.f), fmaxf(h[1], 0.f));
        hp[1] = pk2(fmaxf(h[2], 0.f), fmaxf(h[3], 0.f));
        hp[2] = pk2(fmaxf(h[4], 0.f), 0.f);
        // decoder: 30 dot2
        const uint2* dW = (const uint2*)(lwdU + c * 30);
        uint32_t dreg[30];
        #pragma unroll
        for (int q = 0; q < 15; ++q) { uint2 t = dW[q]; dreg[2*q] = t.x; dreg[2*q+1] = t.y; }
        float acc = 0.f;
        #pragma unroll
        for (int m = 0; m < M; ++m) {
            float r = b_dec[c * 10 + m];
            r = fdot2(hp[0], dreg[m * 3 + 0], r);
            r = fdot2(hp[1], dreg[m * 3 + 1], r);
            r = fdot2(hp[2], dreg[m * 3 + 2], r);
            h2 xv = __builtin_bit_cast(h2, xpk[m >> 1]);
            float xf = (float)((m & 1) ? xv.y : xv.x);
            float d = xf - r;
            acc = __builtin_fmaf(d, d, acc);
        }
        _Float16 ev = (_Float16)__builtin_sqrtf(acc * 0.1f);
        errL[lane * 100 + c] = __builtin_bit_cast(unsigned short, ev);
    };
    #pragma unroll 2
    for (int t = 0; t < 6; ++t) do_cluster(w + 16 * t);
    if (w < 4) do_cluster(w + 96);
    __syncthreads();

    // ---- phase 2: stage meta weights transposed+paired into dead xg ----
    uint32_t* we1U = (uint32_t*)(smem + O_WE1T);  // [j][cp], pitch 26 u32
    uint32_t* wd1U = (uint32_t*)(smem + O_WD1T);  // [c][jp], pitch 26 u32
    for (int i = tid; i < 1250; i += 1024) {
        int j = i / 25, cp = i - j * 25;
        we1U[j * 26 + cp] = pk2(We1[(2 * cp) * 50 + j], We1[(2 * cp + 1) * 50 + j]);
    }
    for (int i = tid; i < 2500; i += 1024) {
        int c = i / 25, jp = i - c * 25;
        wd1U[c * 26 + jp] = pk2(Wd1[(2 * jp) * 100 + c], Wd1[(2 * jp + 1) * 100 + c]);
    }
    __syncthreads();

    // ---- phase 3: meta encoder, all 16 waves; j-pair p = w (+16 if w<9) ----
    uint32_t* hmp = (uint32_t*)(smem + O_HMT);    // [p][lane]
    const uint2* e2 = (const uint2*)(errL + lane * 100);
    auto do_pair = [&](int p) {
        const int j0 = 2 * p;
        float a0 = be1[j0], a1 = be1[j0 + 1];     // uniform s_load
        const uint2* w0 = (const uint2*)(we1U + j0 * 26);
        const uint2* w1 = (const uint2*)(we1U + (j0 + 1) * 26);
        #pragma unroll
        for (int ch = 0; ch < 12; ++ch) {
            uint2 e = e2[ch]; uint2 wa = w0[ch]; uint2 wb = w1[ch];
            a0 = fdot2(e.x, wa.x, a0); a0 = fdot2(e.y, wa.y, a0);
            a1 = fdot2(e.x, wb.x, a1); a1 = fdot2(e.y, wb.y, a1);
        }
        uint32_t et = ((const uint32_t*)e2)[24];
        a0 = fdot2(et, (we1U + j0 * 26)[24], a0);
        a1 = fdot2(et, (we1U + (j0 + 1) * 26)[24], a1);
        hmp[p * 64 + lane] = pk2(fmaxf(a0, 0.f), fmaxf(a1, 0.f));
    };
    do_pair(w);
    if (w < 9) do_pair(w + 16);
    __syncthreads();

    // ---- phase 4: meta decoder + final RMS; wave w -> clusters {w, w+16,...} ----
    uint32_t hmreg[25];
    #pragma unroll
    for (int p = 0; p < 25; ++p) hmreg[p] = hmp[p * 64 + lane];  // conflict-free
    float facc = 0.f;
    auto do_dec = [&](int c) {
        float er = h2f(errL[lane * 100 + c]);
        float r = bd1[c];                          // uniform s_load
        const uint2* wr = (const uint2*)(wd1U + c * 26);
        #pragma unroll
        for (int q = 0; q < 12; ++q) {
            uint2 t = wr[q];
            r = fdot2(hmreg[2 * q], t.x, r);
            r = fdot2(hmreg[2 * q + 1], t.y, r);
        }
        r = fdot2(hmreg[24], (wd1U + c * 26)[24], r);
        float d = er - r;
        facc = __builtin_fmaf(d, d, facc);
    };
    #pragma unroll 2
    for (int t = 0; t < 6; ++t) do_dec(w + 16 * t);
    if (w < 4) do_dec(w + 96);

    float* part = (float*)(smem + O_PART);
    part[w * 64 + lane] = facc;
    __syncthreads();
    if (tid < 64) {
        float s = 0.f;
        #pragma unroll
        for (int i = 0; i < NWAVE; ++i) s += part[i * 64 + tid];
        float fe = __builtin_sqrtf(s * 0.01f);
        out[b0 + tid] = 1.f / (1.f + __expf(-fe));
    }
}

extern "C" void kernel_launch(void* const* d_in, const int* in_sizes, int n_in,
                              void* d_out, int out_size, void* d_ws, size_t ws_size,
                              hipStream_t stream) {
    const float* x     = (const float*)d_in[0];
    const int*   fi    = (const int*)  d_in[1];
    const float* W_enc = (const float*)d_in[2];
    const float* b_enc = (const float*)d_in[3];
    const float* W_dec = (const float*)d_in[4];
    const float* b_dec = (const float*)d_in[5];
    const float* We1   = (const float*)d_in[6];
    const float* be1   = (const float*)d_in[7];
    const float* Wd1   = (const float*)d_in[8];
    const float* bd1   = (const float*)d_in[9];
    float* out = (float*)d_out;

    (void)hipFuncSetAttribute((const void*)kitnet_kernel,
                              hipFuncAttributeMaxDynamicSharedMemorySize, LDS_TOTAL);
    kitnet_kernel<<<65536 / GROUP, 1024, LDS_TOTAL, stream>>>(
        x, fi, W_enc, b_enc, W_dec, b_dec, We1, be1, Wd1, bd1, out);
}